// Round 5
// baseline (134.606 us; speedup 1.0000x reference)
//
#include <hip/hip_runtime.h>
#include <math.h>

#define SEQ 2048
#define DM  1024
#define DI  64

typedef __attribute__((ext_vector_type(8))) short short8;
typedef __attribute__((ext_vector_type(4))) float f32x4;
typedef __attribute__((ext_vector_type(4))) float f4v;
typedef __attribute__((ext_vector_type(4))) unsigned short ush4;

#define MFMA16(a,b,c) __builtin_amdgcn_mfma_f32_16x16x32_bf16(a,b,c,0,0,0)

// round-to-nearest-even fp32 -> bf16 (scalar path; cold/unpaired sites)
__device__ __forceinline__ unsigned short f2bf(float f) {
    unsigned int u = __builtin_bit_cast(unsigned int, f);
    u += 0x7fffu + ((u >> 16) & 1u);
    return (unsigned short)(u >> 16);
}

// packed fp32x2 -> bf16x2 (RNE), 1 VALU op instead of ~8
__device__ __forceinline__ unsigned int cvtpk(float lo, float hi) {
    unsigned int r;
    asm("v_cvt_pk_bf16_f32 %0, %1, %2" : "=v"(r) : "v"(lo), "v"(hi));
    return r;
}

__device__ __forceinline__ float exp2_fast(float x) {
#if __has_builtin(__builtin_amdgcn_exp2f)
    return __builtin_amdgcn_exp2f(x);
#else
    return exp2f(x);
#endif
}

// Wq/bq fold in 0.125 (1/sqrt(dk)) * log2(e) so QK^T lands in exp2 space.
#define QSCALE 0.18033688011112042f   /* 0.125 * 1.4426950408889634 */
#define M0L2   11.541560327111707f    /* 8 * log2(e): fixed-max in exp2 space */

// ---------------------------------------------------------------------------
// Fragment-order layouts (lane = quad*16+n, e = 0..7 contiguous):
//  Wf [g<12][ks<16][s<2][lane][8] : W^T_cat[16g+n][ks*64+s*32+quad*8+e]
//      (rows 0-63 = Wq^T*QSCALE, 64-127 = Wk^T, 128-191 = Wv^T)
//  W0f[g<4][s<2][lane][8]         : W0^T[16g+n][s*32+quad*8+e]
//  Qf/Kf[b][t16<128][s<2][lane][8]: Q[16*t16+n][s*32+quad*8+e]
//  Vf [b][nt<4][kc<32][s<2][lane][8]: V[kc*64+s*32+quad*8+e][16nt+n]
// Every hot-loop global access is base + lane*16 (coalesced, 8 lines/KB).
//
// R5 = R2 (last PASSING, 126.8us) + two semantics-free tweaks:
//  - proj X staging via __builtin_nontemporal_load (X read exactly once;
//    keeps L2 for Wf/Qf/Kf/Vf reuse)
//  - attn: s_setprio(1) around QK^T and PV MFMA clusters (T5; attn blocks
//    are independently-phased -> measured-positive case)
// In-kernel producer/consumer fusion abandoned: 2 consecutive NaN/zero
// failures (R3 cooperative launch rejected by graph capture; R4 cross-block
// visibility NaN, undebuggable without per-kernel counters).
// ---------------------------------------------------------------------------

// Kernel 0: weight prep into fragment order.  98 blocks x 256.
__global__ __launch_bounds__(256)
void convert_kernel(const float* __restrict__ Wq, const float* __restrict__ Wk,
                    const float* __restrict__ Wv, const float* __restrict__ W0,
                    const float* __restrict__ bq, const float* __restrict__ bk,
                    const float* __restrict__ bv,
                    unsigned short* __restrict__ Wf, unsigned short* __restrict__ W0f,
                    float* __restrict__ bcat)
{
    const int t = threadIdx.x;
    const int blk = blockIdx.x;
    if (blk < 96) {
        const int flat = blk * 256 + t;          // 16B block id in Wf
        const int lane = flat & 63;
        const int s    = (flat >> 6) & 1;
        const int gk   = flat >> 7;              // g*16 + ks
        const int g = gk >> 4, ks = gk & 15;
        const int n = lane & 15, quad = lane >> 4;
        const int ocat = 16 * g + n;
        const int mat = ocat >> 6, o = ocat & 63;
        const float* src = (mat == 0) ? Wq : (mat == 1) ? Wk : Wv;
        const float scale = (mat == 0) ? QSCALE : 1.0f;
        const int kb = ks * 64 + s * 32 + quad * 8;
        union { short8 v; unsigned short u[8]; } pk;
#pragma unroll
        for (int e = 0; e < 8; ++e)
            pk.u[e] = f2bf(src[(size_t)(kb + e) * DI + o] * scale);
        *(short8*)(Wf + (size_t)flat * 8) = pk.v;
    } else {
        const int flat = (blk - 96) * 256 + t;   // 16B block id in W0f
        if (flat < 512) {
            const int lane = flat & 63;
            const int s    = (flat >> 6) & 1;
            const int g    = flat >> 7;
            const int n = lane & 15, quad = lane >> 4;
            const int o = 16 * g + n;
            const int kb = s * 32 + quad * 8;
            union { short8 v; unsigned short u[8]; } pk;
#pragma unroll
            for (int e = 0; e < 8; ++e)
                pk.u[e] = f2bf(W0[(size_t)(kb + e) * DI + o]);
            *(short8*)(W0f + (size_t)flat * 8) = pk.v;
        }
        if (blk == 96 && t < 192)
            bcat[t] = (t < 64) ? bq[t] * QSCALE : (t < 128) ? bk[t - 64] : bv[t - 128];
    }
}

// ---------------------------------------------------------------------------
// Kernel 1: QKV projection, 32-token tiles.
// ---------------------------------------------------------------------------
__global__ __launch_bounds__(256, 2)
void proj_kernel(const float* __restrict__ X, const unsigned short* __restrict__ Wf,
                 const float* __restrict__ bcat,
                 unsigned short* __restrict__ Qf, unsigned short* __restrict__ Kf,
                 unsigned short* __restrict__ Vf)
{
    __shared__ alignas(16) unsigned short Xs[32 * 1024];   // 64 KB, frag-order x2
    const int t = threadIdx.x;
    const int lane = t & 63, w = t >> 6;
    const int quad = lane >> 4, n = lane & 15;
    const int r0 = blockIdx.x * 32;

    // ---- stage X tile once: fp32 coalesced (non-temporal) -> bf16 LDS ----
    {
        const int r = t >> 4, g = t & 15;                  // row-in-16, col-group
        const int s = g >> 3, qd = (g >> 1) & 3, e0 = (g & 1) * 4;
        const int base = (r * 4 + qd) * 8 + e0;            // lane-permuted slot
#pragma unroll
        for (int th = 0; th < 2; ++th) {
            const float* xp = X + (size_t)(r0 + th * 16 + r) * DM + g * 4;
#pragma unroll
            for (int i = 0; i < 16; ++i) {
                const f4v x = __builtin_nontemporal_load((const f4v*)(xp + i * 64));
                union { unsigned int wd[2]; ush4 v; } px;
                px.wd[0] = cvtpk(x[0], x[1]);
                px.wd[1] = cvtpk(x[2], x[3]);
                *(ush4*)(Xs + th * 16384 + (i * 2 + s) * 512 + base) = px.v;
            }
        }
    }
    __syncthreads();

    const unsigned short* wb0 = Wf + (size_t)(3 * w + 0) * 16384 + lane * 8;
    const unsigned short* wb1 = Wf + (size_t)(3 * w + 1) * 16384 + lane * 8;
    const unsigned short* wb2 = Wf + (size_t)(3 * w + 2) * 16384 + lane * 8;
    const int aperm = (n * 4 + quad) * 8;                  // matches staging perm

    const f32x4 ZERO = {0.f, 0.f, 0.f, 0.f};
    f32x4 acc[2][3];
#pragma unroll
    for (int th = 0; th < 2; ++th)
#pragma unroll
        for (int j = 0; j < 3; ++j) acc[th][j] = ZERO;

    // ---- barrier-free K loop ----
#pragma unroll 2
    for (int ks = 0; ks < 16; ++ks) {
        short8 af[2][2], bf[3][2];
#pragma unroll
        for (int s = 0; s < 2; ++s) {
            const size_t o = (size_t)(ks * 2 + s) * 512;
            af[0][s] = *(const short8*)(Xs + o + aperm);
            af[1][s] = *(const short8*)(Xs + 16384 + o + aperm);
            bf[0][s] = *(const short8*)(wb0 + o);
            bf[1][s] = *(const short8*)(wb1 + o);
            bf[2][s] = *(const short8*)(wb2 + o);
        }
#pragma unroll
        for (int th = 0; th < 2; ++th)
#pragma unroll
            for (int j = 0; j < 3; ++j) {
                acc[th][j] = MFMA16(af[th][0], bf[j][0], acc[th][j]);
                acc[th][j] = MFMA16(af[th][1], bf[j][1], acc[th][j]);
            }
    }

    __syncthreads();                                       // all Xs reads done
    unsigned short (*Facc)[200] = (unsigned short (*)[200])Xs;   // 12.8 KB reuse
    // epilogue: D layout col = n (out-in-tile), row = quad*4+r (token-in-16)
    float bias[3];
#pragma unroll
    for (int j = 0; j < 3; ++j) bias[j] = bcat[(3 * w + j) * 16 + n];
#pragma unroll
    for (int th = 0; th < 2; ++th)
#pragma unroll
        for (int j = 0; j < 3; ++j)
#pragma unroll
            for (int r = 0; r < 4; ++r)
                Facc[th * 16 + quad * 4 + r][(3 * w + j) * 16 + n] = f2bf(acc[th][j][r] + bias[j]);
    __syncthreads();

    const int bidx = r0 >> 11;
    const int qt16 = (r0 >> 4) & 127;          // within-batch 16-token group
    const int kc   = (r0 >> 6) & 31;           // 64-key chunk
    const int sblk = (r0 >> 5) & 1;            // 32-key half within chunk
    // Q/K frag-order stores: thread t -> (qsel, s, lane')
    {
        const int qsel = t >> 7, s = (t >> 6) & 1, lp = t & 63;
        const int np = lp & 15, qp = lp >> 4;
        const int row = qsel * 16 + np, col = s * 32 + qp * 8;
        const size_t off = (size_t)(((bidx * 128 + qt16 + qsel) * 2 + s) * 64 + lp) * 8;
        *(short8*)(Qf + off) = *(const short8*)&Facc[row][col];
        *(short8*)(Kf + off) = *(const short8*)&Facc[row][64 + col];
    }
    // V frag-order store: thread t -> (nt, lane')
    {
        const int nt = t >> 6, lp = t & 63;
        const int np = lp & 15, qp = lp >> 4;
        union { short8 v; unsigned short u[8]; } ov;
#pragma unroll
        for (int e = 0; e < 8; ++e) ov.u[e] = Facc[qp * 8 + e][128 + 16 * nt + np];
        const size_t off = (size_t)((((bidx * 4 + nt) * 32 + kc) * 2 + sblk) * 64 + lp) * 8;
        *(short8*)(Vf + off) = ov.v;
    }
}

// ---------------------------------------------------------------------------
// Kernel 2: split-K flash attention + fused W0, fixed-max softmax in exp2
// space.  Dual-chunk + cross-iteration prefetch + balanced CU pairing +
// setprio around MFMA clusters.
// ---------------------------------------------------------------------------
__global__ __launch_bounds__(256, 2)
void attn_kernel(const unsigned short* __restrict__ Qf, const unsigned short* __restrict__ Kf,
                 const unsigned short* __restrict__ Vf, const unsigned short* __restrict__ W0f,
                 const float* __restrict__ b0, float* __restrict__ Out)
{
    __shared__ alignas(16) float pool[4][32][72];         // per-wave Ctx f32 (P0/P1 live here)
    __shared__ alignas(16) unsigned short Cb[32][72];     // merged ctx, bf16 A-frag layout
    __shared__ float Lp[4][32][4];                        // per-wave per-quad rsum partials

    const int t = threadIdx.x;
    const int lane = t & 63, w = t >> 6;
    const int quad = lane >> 4, n = lane & 15;
    const int g  = blockIdx.x >> 3;
    const int qt = (g < 32) ? (63 - g) : (g - 32);        // CU-paired: C sums to 33
    const int b  = blockIdx.x & 7;
    const int q0 = qt * 32;

    unsigned short* P0 = (unsigned short*)&pool[w][0][0]; // [32][72] bf16
    unsigned short* P1 = P0 + 32 * 72;                    // second buffer (4608 B each)

    short8 qf[2][2];
#pragma unroll
    for (int qh = 0; qh < 2; ++qh)
#pragma unroll
        for (int s = 0; s < 2; ++s)
            qf[qh][s] = *(const short8*)(Qf + (size_t)(((b*128 + qt*2 + qh)*2 + s)*64 + lane) * 8);

    const f32x4 ZERO = {0.f, 0.f, 0.f, 0.f};
    f32x4 ctx[2][4];
#pragma unroll
    for (int qh = 0; qh < 2; ++qh)
#pragma unroll
        for (int nt = 0; nt < 4; ++nt) ctx[qh][nt] = ZERO;
    float rs2[2][2] = {{0.f, 0.f}, {0.f, 0.f}};

    const int C = (qt >> 1) + 1;                          // causal 64-key chunks

#define DO_CHUNK(KT, PB, KFX, VFX)                                             \
    do {                                                                       \
        const int k0_ = (KT) * 64;                                             \
        f32x4 sv[2][4];                                                        \
        __builtin_amdgcn_s_setprio(1);                                         \
        _Pragma("unroll")                                                      \
        for (int qh = 0; qh < 2; ++qh)                                         \
            _Pragma("unroll")                                                  \
            for (int tt = 0; tt < 4; ++tt) {                                   \
                f32x4 a_ = MFMA16(KFX[tt][0], qf[qh][0], ZERO);                \
                sv[qh][tt] = MFMA16(KFX[tt][1], qf[qh][1], a_);                \
            }                                                                  \
        __builtin_amdgcn_s_setprio(0);                                         \
        if ((KT) == C - 1) {                                                   \
            _Pragma("unroll")                                                  \
            for (int qh = 0; qh < 2; ++qh)                                     \
                _Pragma("unroll")                                              \
                for (int tt = 0; tt < 4; ++tt)                                 \
                    _Pragma("unroll")                                          \
                    for (int r = 0; r < 4; ++r)                                \
                        if (k0_ + 16*tt + quad*4 + r > q0 + qh*16 + n)         \
                            sv[qh][tt][r] = -INFINITY;                         \
        }                                                                      \
        _Pragma("unroll")                                                      \
        for (int qh = 0; qh < 2; ++qh)                                         \
            _Pragma("unroll")                                                  \
            for (int tt = 0; tt < 4; ++tt) {                                   \
                float p_[4];                                                   \
                _Pragma("unroll")                                              \
                for (int r = 0; r < 4; ++r) {                                  \
                    p_[r] = exp2_fast(sv[qh][tt][r] - M0L2);                   \
                    rs2[qh][r & 1] += p_[r];                                   \
                }                                                              \
                union { unsigned int wd[2]; ush4 v; } pw;                      \
                pw.wd[0] = cvtpk(p_[0], p_[1]);                                \
                pw.wd[1] = cvtpk(p_[2], p_[3]);                                \
                *(ush4*)&(PB)[(size_t)(qh*16 + n) * 72 + 16*tt + quad*4] = pw.v; \
            }                                                                  \
        __builtin_amdgcn_s_setprio(1);                                         \
        _Pragma("unroll")                                                      \
        for (int s = 0; s < 2; ++s) {                                          \
            const short8 pf0 = *(const short8*)&(PB)[(size_t)(n)      * 72 + s*32 + quad*8]; \
            const short8 pf1 = *(const short8*)&(PB)[(size_t)(16 + n) * 72 + s*32 + quad*8]; \
            _Pragma("unroll")                                                  \
            for (int nt = 0; nt < 4; ++nt) {                                   \
                ctx[0][nt] = MFMA16(pf0, VFX[nt][s], ctx[0][nt]);              \
                ctx[1][nt] = MFMA16(pf1, VFX[nt][s], ctx[1][nt]);              \
            }                                                                  \
        }                                                                      \
        __builtin_amdgcn_s_setprio(0);                                         \
    } while (0)

    // preload A-set for the first outer iteration
    short8 kfA[4][2], vfA[4][2];
    if (w < C) {
#pragma unroll
        for (int tt = 0; tt < 4; ++tt)
#pragma unroll
            for (int s = 0; s < 2; ++s) {
                kfA[tt][s] = *(const short8*)(Kf + (size_t)(((b*128 + w*4 + tt)*2 + s)*64 + lane) * 8);
                vfA[tt][s] = *(const short8*)(Vf + (size_t)((((b*4 + tt)*32 + w)*2 + s)*64 + lane) * 8);
            }
    }
    for (int kt0 = w; kt0 < C; kt0 += 8) {
        const int ktB = kt0 + 4;
        const bool hasB = (ktB < C);
        short8 kfB[4][2];
        if (hasB) {                                       // K(B) before chunk A: covered by A
#pragma unroll
            for (int tt = 0; tt < 4; ++tt)
#pragma unroll
                for (int s = 0; s < 2; ++s)
                    kfB[tt][s] = *(const short8*)(Kf + (size_t)(((b*128 + ktB*4 + tt)*2 + s)*64 + lane) * 8);
        }
        DO_CHUNK(kt0, P0, kfA, vfA);
        // prefetch next iteration's A-set: covered by chunk B's whole chain
        const int ktN = kt0 + 8;
        const bool hasN = (ktN < C);
        short8 kfN[4][2], vfN[4][2];
        if (hasN) {
#pragma unroll
            for (int tt = 0; tt < 4; ++tt)
#pragma unroll
                for (int s = 0; s < 2; ++s) {
                    kfN[tt][s] = *(const short8*)(Kf + (size_t)(((b*128 + ktN*4 + tt)*2 + s)*64 + lane) * 8);
                    vfN[tt][s] = *(const short8*)(Vf + (size_t)((((b*4 + tt)*32 + ktN)*2 + s)*64 + lane) * 8);
                }
        }
        if (hasB) {
            short8 vfB[4][2];
#pragma unroll
            for (int tt = 0; tt < 4; ++tt)
#pragma unroll
                for (int s = 0; s < 2; ++s)
                    vfB[tt][s] = *(const short8*)(Vf + (size_t)((((b*4 + tt)*32 + ktB)*2 + s)*64 + lane) * 8);
            DO_CHUNK(ktB, P1, kfB, vfB);
        }
        if (hasN) {
#pragma unroll
            for (int tt = 0; tt < 4; ++tt)
#pragma unroll
                for (int s = 0; s < 2; ++s) {
                    kfA[tt][s] = kfN[tt][s];
                    vfA[tt][s] = vfN[tt][s];
                }
        }
    }
#undef DO_CHUNK

    // publish per-wave partials (overwrites own P region; same-wave DS order)
#pragma unroll
    for (int qh = 0; qh < 2; ++qh) {
#pragma unroll
        for (int nt = 0; nt < 4; ++nt)
#pragma unroll
            for (int r = 0; r < 4; ++r)
                pool[w][qh*16 + quad*4 + r][nt*16 + n] = ctx[qh][nt][r];
        Lp[w][qh*16 + n][quad] = rs2[qh][0] + rs2[qh][1];
    }
    __syncthreads();

    // merge (plain sums): thread t -> q = t>>3, dv cols (t&7)*8 .. +7
    {
        const int q = t >> 3, c0 = (t & 7) * 8;
        float l = 0.f;
#pragma unroll
        for (int w4 = 0; w4 < 4; ++w4)
#pragma unroll
            for (int qd = 0; qd < 4; ++qd) l += Lp[w4][q][qd];
        const float inv = 1.0f / l;
        float s[8];
#pragma unroll
        for (int j = 0; j < 8; ++j) s[j] = 0.f;
#pragma unroll
        for (int w4 = 0; w4 < 4; ++w4) {
            const float4 a = *(const float4*)&pool[w4][q][c0];
            const float4 c = *(const float4*)&pool[w4][q][c0 + 4];
            s[0] += a.x; s[1] += a.y; s[2] += a.z; s[3] += a.w;
            s[4] += c.x; s[5] += c.y; s[6] += c.z; s[7] += c.w;
        }
        union { unsigned int wd[4]; short8 v; } cb;
#pragma unroll
        for (int j = 0; j < 4; ++j)
            cb.wd[j] = cvtpk(s[2*j] * inv, s[2*j + 1] * inv);
        *(short8*)&Cb[q][c0] = cb.v;
    }
    __syncthreads();

    // W0 epilogue: wave w -> out cols 16w..16w+15 (W0f frag-order loads)
    f32x4 oacc[2] = {ZERO, ZERO};
#pragma unroll
    for (int s = 0; s < 2; ++s) {
        const short8 wf = *(const short8*)(W0f + (size_t)((w*2 + s)*64 + lane) * 8);
#pragma unroll
        for (int tt = 0; tt < 2; ++tt) {
            const short8 cf = *(const short8*)&Cb[tt*16 + n][s*32 + quad*8];
            oacc[tt] = MFMA16(cf, wf, oacc[tt]);
        }
    }
    const float bb = b0[16*w + n];
#pragma unroll
    for (int tt = 0; tt < 2; ++tt)
#pragma unroll
        for (int r = 0; r < 4; ++r)
            Out[((size_t)b * SEQ + q0 + tt*16 + quad*4 + r) * DI + 16*w + n] = oacc[tt][r] + bb;
}

// ---------------------------------------------------------------------------
extern "C" void kernel_launch(void* const* d_in, const int* in_sizes, int n_in,
                              void* d_out, int out_size, void* d_ws, size_t ws_size,
                              hipStream_t stream) {
    const float* X  = (const float*)d_in[0];
    const float* Wk = (const float*)d_in[1];
    const float* bk = (const float*)d_in[2];
    const float* Wq = (const float*)d_in[3];
    const float* bq = (const float*)d_in[4];
    const float* Wv = (const float*)d_in[5];
    const float* bv = (const float*)d_in[6];
    const float* W0 = (const float*)d_in[7];
    const float* b0 = (const float*)d_in[8];
    float* Out = (float*)d_out;

    unsigned char* ws = (unsigned char*)d_ws;
    unsigned short* Wf   = (unsigned short*)ws;                       // 384 KiB
    unsigned short* W0f  = (unsigned short*)(ws + 393216);            // 8 KiB
    float*          bcat = (float*)(ws + 401408);                     // 768 B
    unsigned short* Qf   = (unsigned short*)(ws + 409600);            // 2 MiB
    unsigned short* Kf   = (unsigned short*)(ws + 409600 + 2097152);  // 2 MiB
    unsigned short* Vf   = (unsigned short*)(ws + 409600 + 4194304);  // 2 MiB

    convert_kernel<<<98, 256, 0, stream>>>(Wq, Wk, Wv, W0, bq, bk, bv, Wf, W0f, bcat);
    proj_kernel<<<512, 256, 0, stream>>>(X, Wf, bcat, Qf, Kf, Vf);
    attn_kernel<<<512, 256, 0, stream>>>(Qf, Kf, Vf, W0f, b0, Out);
}

// Round 6
// 124.408 us; speedup vs baseline: 1.0820x; 1.0820x over previous
//
#include <hip/hip_runtime.h>
#include <math.h>

#define SEQ 2048
#define DM  1024
#define DI  64

typedef __attribute__((ext_vector_type(8))) short short8;
typedef __attribute__((ext_vector_type(4))) float f32x4;
typedef __attribute__((ext_vector_type(4))) unsigned short ush4;

#define MFMA16(a,b,c) __builtin_amdgcn_mfma_f32_16x16x32_bf16(a,b,c,0,0,0)

// round-to-nearest-even fp32 -> bf16 (scalar path; cold/unpaired sites)
__device__ __forceinline__ unsigned short f2bf(float f) {
    unsigned int u = __builtin_bit_cast(unsigned int, f);
    u += 0x7fffu + ((u >> 16) & 1u);
    return (unsigned short)(u >> 16);
}

// packed fp32x2 -> bf16x2 (RNE), 1 VALU op instead of ~8
__device__ __forceinline__ unsigned int cvtpk(float lo, float hi) {
    unsigned int r;
    asm("v_cvt_pk_bf16_f32 %0, %1, %2" : "=v"(r) : "v"(lo), "v"(hi));
    return r;
}

__device__ __forceinline__ float exp2_fast(float x) {
#if __has_builtin(__builtin_amdgcn_exp2f)
    return __builtin_amdgcn_exp2f(x);
#else
    return exp2f(x);
#endif
}

// Wq/bq fold in 0.125 (1/sqrt(dk)) * log2(e) so QK^T lands in exp2 space.
#define QSCALE 0.18033688011112042f   /* 0.125 * 1.4426950408889634 */
#define M0L2   11.541560327111707f    /* 8 * log2(e): fixed-max in exp2 space */

// ---------------------------------------------------------------------------
// Fragment-order layouts (lane = quad*16+n, e = 0..7 contiguous):
//  Wf [g<12][ks<16][s<2][lane][8] : W^T_cat[16g+n][ks*64+s*32+quad*8+e]
//      (rows 0-63 = Wq^T*QSCALE, 64-127 = Wk^T, 128-191 = Wv^T)
//  W0f[g<4][s<2][lane][8]         : W0^T[16g+n][s*32+quad*8+e]
//  Qf/Kf[b][t16<128][s<2][lane][8]: Q[16*t16+n][s*32+quad*8+e]
//  Vf [b][nt<4][kc<32][s<2][lane][8]: V[kc*64+s*32+quad*8+e][16nt+n]
// Every hot-loop global access is base + lane*16 (coalesced, 8 lines/KB).
//
// R6 = exact revert to R2 (session best, 126.8us).  R5's two "safe" tweaks
// (nontemporal X loads, setprio around MFMA) both regressed ~4-5us beyond
// container noise; removed.  Fusion attempts (R3 cooperative, R4 flag-based)
// both failed correctness; abandoned.
// ---------------------------------------------------------------------------

// Kernel 0: weight prep into fragment order.  98 blocks x 256.
__global__ __launch_bounds__(256)
void convert_kernel(const float* __restrict__ Wq, const float* __restrict__ Wk,
                    const float* __restrict__ Wv, const float* __restrict__ W0,
                    const float* __restrict__ bq, const float* __restrict__ bk,
                    const float* __restrict__ bv,
                    unsigned short* __restrict__ Wf, unsigned short* __restrict__ W0f,
                    float* __restrict__ bcat)
{
    const int t = threadIdx.x;
    const int blk = blockIdx.x;
    if (blk < 96) {
        const int flat = blk * 256 + t;          // 16B block id in Wf
        const int lane = flat & 63;
        const int s    = (flat >> 6) & 1;
        const int gk   = flat >> 7;              // g*16 + ks
        const int g = gk >> 4, ks = gk & 15;
        const int n = lane & 15, quad = lane >> 4;
        const int ocat = 16 * g + n;
        const int mat = ocat >> 6, o = ocat & 63;
        const float* src = (mat == 0) ? Wq : (mat == 1) ? Wk : Wv;
        const float scale = (mat == 0) ? QSCALE : 1.0f;
        const int kb = ks * 64 + s * 32 + quad * 8;
        union { short8 v; unsigned short u[8]; } pk;
#pragma unroll
        for (int e = 0; e < 8; ++e)
            pk.u[e] = f2bf(src[(size_t)(kb + e) * DI + o] * scale);
        *(short8*)(Wf + (size_t)flat * 8) = pk.v;
    } else {
        const int flat = (blk - 96) * 256 + t;   // 16B block id in W0f
        if (flat < 512) {
            const int lane = flat & 63;
            const int s    = (flat >> 6) & 1;
            const int g    = flat >> 7;
            const int n = lane & 15, quad = lane >> 4;
            const int o = 16 * g + n;
            const int kb = s * 32 + quad * 8;
            union { short8 v; unsigned short u[8]; } pk;
#pragma unroll
            for (int e = 0; e < 8; ++e)
                pk.u[e] = f2bf(W0[(size_t)(kb + e) * DI + o]);
            *(short8*)(W0f + (size_t)flat * 8) = pk.v;
        }
        if (blk == 96 && t < 192)
            bcat[t] = (t < 64) ? bq[t] * QSCALE : (t < 128) ? bk[t - 64] : bv[t - 128];
    }
}

// ---------------------------------------------------------------------------
// Kernel 1: QKV projection, 32-token tiles.  (R13 structure; staging pack
// uses v_cvt_pk_bf16_f32 — 2 VALU per float4 instead of ~16.)
// ---------------------------------------------------------------------------
__global__ __launch_bounds__(256, 2)
void proj_kernel(const float* __restrict__ X, const unsigned short* __restrict__ Wf,
                 const float* __restrict__ bcat,
                 unsigned short* __restrict__ Qf, unsigned short* __restrict__ Kf,
                 unsigned short* __restrict__ Vf)
{
    __shared__ alignas(16) unsigned short Xs[32 * 1024];   // 64 KB, frag-order x2
    const int t = threadIdx.x;
    const int lane = t & 63, w = t >> 6;
    const int quad = lane >> 4, n = lane & 15;
    const int r0 = blockIdx.x * 32;

    // ---- stage X tile once: fp32 coalesced -> bf16 frag-order LDS ----
    {
        const int r = t >> 4, g = t & 15;                  // row-in-16, col-group
        const int s = g >> 3, qd = (g >> 1) & 3, e0 = (g & 1) * 4;
        const int base = (r * 4 + qd) * 8 + e0;            // lane-permuted slot
#pragma unroll
        for (int th = 0; th < 2; ++th) {
            const float* xp = X + (size_t)(r0 + th * 16 + r) * DM + g * 4;
#pragma unroll
            for (int i = 0; i < 16; ++i) {
                const float4 x = *(const float4*)(xp + i * 64);
                union { unsigned int wd[2]; ush4 v; } px;
                px.wd[0] = cvtpk(x.x, x.y);
                px.wd[1] = cvtpk(x.z, x.w);
                *(ush4*)(Xs + th * 16384 + (i * 2 + s) * 512 + base) = px.v;
            }
        }
    }
    __syncthreads();

    const unsigned short* wb0 = Wf + (size_t)(3 * w + 0) * 16384 + lane * 8;
    const unsigned short* wb1 = Wf + (size_t)(3 * w + 1) * 16384 + lane * 8;
    const unsigned short* wb2 = Wf + (size_t)(3 * w + 2) * 16384 + lane * 8;
    const int aperm = (n * 4 + quad) * 8;                  // matches staging perm

    const f32x4 ZERO = {0.f, 0.f, 0.f, 0.f};
    f32x4 acc[2][3];
#pragma unroll
    for (int th = 0; th < 2; ++th)
#pragma unroll
        for (int j = 0; j < 3; ++j) acc[th][j] = ZERO;

    // ---- barrier-free K loop ----
#pragma unroll 2
    for (int ks = 0; ks < 16; ++ks) {
        short8 af[2][2], bf[3][2];
#pragma unroll
        for (int s = 0; s < 2; ++s) {
            const size_t o = (size_t)(ks * 2 + s) * 512;
            af[0][s] = *(const short8*)(Xs + o + aperm);
            af[1][s] = *(const short8*)(Xs + 16384 + o + aperm);
            bf[0][s] = *(const short8*)(wb0 + o);
            bf[1][s] = *(const short8*)(wb1 + o);
            bf[2][s] = *(const short8*)(wb2 + o);
        }
#pragma unroll
        for (int th = 0; th < 2; ++th)
#pragma unroll
            for (int j = 0; j < 3; ++j) {
                acc[th][j] = MFMA16(af[th][0], bf[j][0], acc[th][j]);
                acc[th][j] = MFMA16(af[th][1], bf[j][1], acc[th][j]);
            }
    }

    __syncthreads();                                       // all Xs reads done
    unsigned short (*Facc)[200] = (unsigned short (*)[200])Xs;   // 12.8 KB reuse
    // epilogue: D layout col = n (out-in-tile), row = quad*4+r (token-in-16)
    float bias[3];
#pragma unroll
    for (int j = 0; j < 3; ++j) bias[j] = bcat[(3 * w + j) * 16 + n];
#pragma unroll
    for (int th = 0; th < 2; ++th)
#pragma unroll
        for (int j = 0; j < 3; ++j)
#pragma unroll
            for (int r = 0; r < 4; ++r)
                Facc[th * 16 + quad * 4 + r][(3 * w + j) * 16 + n] = f2bf(acc[th][j][r] + bias[j]);
    __syncthreads();

    const int bidx = r0 >> 11;
    const int qt16 = (r0 >> 4) & 127;          // within-batch 16-token group
    const int kc   = (r0 >> 6) & 31;           // 64-key chunk
    const int sblk = (r0 >> 5) & 1;            // 32-key half within chunk
    // Q/K frag-order stores: thread t -> (qsel, s, lane')
    {
        const int qsel = t >> 7, s = (t >> 6) & 1, lp = t & 63;
        const int np = lp & 15, qp = lp >> 4;
        const int row = qsel * 16 + np, col = s * 32 + qp * 8;
        const size_t off = (size_t)(((bidx * 128 + qt16 + qsel) * 2 + s) * 64 + lp) * 8;
        *(short8*)(Qf + off) = *(const short8*)&Facc[row][col];
        *(short8*)(Kf + off) = *(const short8*)&Facc[row][64 + col];
    }
    // V frag-order store: thread t -> (nt, lane')
    {
        const int nt = t >> 6, lp = t & 63;
        const int np = lp & 15, qp = lp >> 4;
        union { short8 v; unsigned short u[8]; } ov;
#pragma unroll
        for (int e = 0; e < 8; ++e) ov.u[e] = Facc[qp * 8 + e][128 + 16 * nt + np];
        const size_t off = (size_t)((((bidx * 4 + nt) * 32 + kc) * 2 + sblk) * 64 + lp) * 8;
        *(short8*)(Vf + off) = ov.v;
    }
}

// ---------------------------------------------------------------------------
// Kernel 2: split-K flash attention + fused W0, fixed-max softmax in exp2
// space.  Dual-chunk + cross-iteration prefetch + balanced CU pairing:
//  (1) blocks i and i+256 land on the same CU (round-robin dispatch), so the
//      qt map pairs heavy-descending with light-ASCENDING halves -> every
//      CU's two blocks sum to exactly 33 causal chunks.
//  (2) softmax pack via v_cvt_pk_bf16_f32 and exp2-space scores
//      (v_exp_f32 with no pre-multiply), rs chain split.
// ---------------------------------------------------------------------------
__global__ __launch_bounds__(256, 2)
void attn_kernel(const unsigned short* __restrict__ Qf, const unsigned short* __restrict__ Kf,
                 const unsigned short* __restrict__ Vf, const unsigned short* __restrict__ W0f,
                 const float* __restrict__ b0, float* __restrict__ Out)
{
    __shared__ alignas(16) float pool[4][32][72];         // per-wave Ctx f32 (P0/P1 live here)
    __shared__ alignas(16) unsigned short Cb[32][72];     // merged ctx, bf16 A-frag layout
    __shared__ float Lp[4][32][4];                        // per-wave per-quad rsum partials

    const int t = threadIdx.x;
    const int lane = t & 63, w = t >> 6;
    const int quad = lane >> 4, n = lane & 15;
    const int g  = blockIdx.x >> 3;
    const int qt = (g < 32) ? (63 - g) : (g - 32);        // CU-paired: C sums to 33
    const int b  = blockIdx.x & 7;
    const int q0 = qt * 32;

    unsigned short* P0 = (unsigned short*)&pool[w][0][0]; // [32][72] bf16
    unsigned short* P1 = P0 + 32 * 72;                    // second buffer (4608 B each)

    short8 qf[2][2];
#pragma unroll
    for (int qh = 0; qh < 2; ++qh)
#pragma unroll
        for (int s = 0; s < 2; ++s)
            qf[qh][s] = *(const short8*)(Qf + (size_t)(((b*128 + qt*2 + qh)*2 + s)*64 + lane) * 8);

    const f32x4 ZERO = {0.f, 0.f, 0.f, 0.f};
    f32x4 ctx[2][4];
#pragma unroll
    for (int qh = 0; qh < 2; ++qh)
#pragma unroll
        for (int nt = 0; nt < 4; ++nt) ctx[qh][nt] = ZERO;
    float rs2[2][2] = {{0.f, 0.f}, {0.f, 0.f}};

    const int C = (qt >> 1) + 1;                          // causal 64-key chunks

#define DO_CHUNK(KT, PB, KFX, VFX)                                             \
    do {                                                                       \
        const int k0_ = (KT) * 64;                                             \
        f32x4 sv[2][4];                                                        \
        _Pragma("unroll")                                                      \
        for (int qh = 0; qh < 2; ++qh)                                         \
            _Pragma("unroll")                                                  \
            for (int tt = 0; tt < 4; ++tt) {                                   \
                f32x4 a_ = MFMA16(KFX[tt][0], qf[qh][0], ZERO);                \
                sv[qh][tt] = MFMA16(KFX[tt][1], qf[qh][1], a_);                \
            }                                                                  \
        if ((KT) == C - 1) {                                                   \
            _Pragma("unroll")                                                  \
            for (int qh = 0; qh < 2; ++qh)                                     \
                _Pragma("unroll")                                              \
                for (int tt = 0; tt < 4; ++tt)                                 \
                    _Pragma("unroll")                                          \
                    for (int r = 0; r < 4; ++r)                                \
                        if (k0_ + 16*tt + quad*4 + r > q0 + qh*16 + n)         \
                            sv[qh][tt][r] = -INFINITY;                         \
        }                                                                      \
        _Pragma("unroll")                                                      \
        for (int qh = 0; qh < 2; ++qh)                                         \
            _Pragma("unroll")                                                  \
            for (int tt = 0; tt < 4; ++tt) {                                   \
                float p_[4];                                                   \
                _Pragma("unroll")                                              \
                for (int r = 0; r < 4; ++r) {                                  \
                    p_[r] = exp2_fast(sv[qh][tt][r] - M0L2);                   \
                    rs2[qh][r & 1] += p_[r];                                   \
                }                                                              \
                union { unsigned int wd[2]; ush4 v; } pw;                      \
                pw.wd[0] = cvtpk(p_[0], p_[1]);                                \
                pw.wd[1] = cvtpk(p_[2], p_[3]);                                \
                *(ush4*)&(PB)[(size_t)(qh*16 + n) * 72 + 16*tt + quad*4] = pw.v; \
            }                                                                  \
        _Pragma("unroll")                                                      \
        for (int s = 0; s < 2; ++s) {                                          \
            const short8 pf0 = *(const short8*)&(PB)[(size_t)(n)      * 72 + s*32 + quad*8]; \
            const short8 pf1 = *(const short8*)&(PB)[(size_t)(16 + n) * 72 + s*32 + quad*8]; \
            _Pragma("unroll")                                                  \
            for (int nt = 0; nt < 4; ++nt) {                                   \
                ctx[0][nt] = MFMA16(pf0, VFX[nt][s], ctx[0][nt]);              \
                ctx[1][nt] = MFMA16(pf1, VFX[nt][s], ctx[1][nt]);              \
            }                                                                  \
        }                                                                      \
    } while (0)

    // preload A-set for the first outer iteration
    short8 kfA[4][2], vfA[4][2];
    if (w < C) {
#pragma unroll
        for (int tt = 0; tt < 4; ++tt)
#pragma unroll
            for (int s = 0; s < 2; ++s) {
                kfA[tt][s] = *(const short8*)(Kf + (size_t)(((b*128 + w*4 + tt)*2 + s)*64 + lane) * 8);
                vfA[tt][s] = *(const short8*)(Vf + (size_t)((((b*4 + tt)*32 + w)*2 + s)*64 + lane) * 8);
            }
    }
    for (int kt0 = w; kt0 < C; kt0 += 8) {
        const int ktB = kt0 + 4;
        const bool hasB = (ktB < C);
        short8 kfB[4][2];
        if (hasB) {                                       // K(B) before chunk A: covered by A
#pragma unroll
            for (int tt = 0; tt < 4; ++tt)
#pragma unroll
                for (int s = 0; s < 2; ++s)
                    kfB[tt][s] = *(const short8*)(Kf + (size_t)(((b*128 + ktB*4 + tt)*2 + s)*64 + lane) * 8);
        }
        DO_CHUNK(kt0, P0, kfA, vfA);
        // prefetch next iteration's A-set: covered by chunk B's whole chain
        const int ktN = kt0 + 8;
        const bool hasN = (ktN < C);
        short8 kfN[4][2], vfN[4][2];
        if (hasN) {
#pragma unroll
            for (int tt = 0; tt < 4; ++tt)
#pragma unroll
                for (int s = 0; s < 2; ++s) {
                    kfN[tt][s] = *(const short8*)(Kf + (size_t)(((b*128 + ktN*4 + tt)*2 + s)*64 + lane) * 8);
                    vfN[tt][s] = *(const short8*)(Vf + (size_t)((((b*4 + tt)*32 + ktN)*2 + s)*64 + lane) * 8);
                }
        }
        if (hasB) {
            short8 vfB[4][2];
#pragma unroll
            for (int tt = 0; tt < 4; ++tt)
#pragma unroll
                for (int s = 0; s < 2; ++s)
                    vfB[tt][s] = *(const short8*)(Vf + (size_t)((((b*4 + tt)*32 + ktB)*2 + s)*64 + lane) * 8);
            DO_CHUNK(ktB, P1, kfB, vfB);
        }
        if (hasN) {
#pragma unroll
            for (int tt = 0; tt < 4; ++tt)
#pragma unroll
                for (int s = 0; s < 2; ++s) {
                    kfA[tt][s] = kfN[tt][s];
                    vfA[tt][s] = vfN[tt][s];
                }
        }
    }
#undef DO_CHUNK

    // publish per-wave partials (overwrites own P region; same-wave DS order)
#pragma unroll
    for (int qh = 0; qh < 2; ++qh) {
#pragma unroll
        for (int nt = 0; nt < 4; ++nt)
#pragma unroll
            for (int r = 0; r < 4; ++r)
                pool[w][qh*16 + quad*4 + r][nt*16 + n] = ctx[qh][nt][r];
        Lp[w][qh*16 + n][quad] = rs2[qh][0] + rs2[qh][1];
    }
    __syncthreads();

    // merge (plain sums): thread t -> q = t>>3, dv cols (t&7)*8 .. +7
    {
        const int q = t >> 3, c0 = (t & 7) * 8;
        float l = 0.f;
#pragma unroll
        for (int w4 = 0; w4 < 4; ++w4)
#pragma unroll
            for (int qd = 0; qd < 4; ++qd) l += Lp[w4][q][qd];
        const float inv = 1.0f / l;
        float s[8];
#pragma unroll
        for (int j = 0; j < 8; ++j) s[j] = 0.f;
#pragma unroll
        for (int w4 = 0; w4 < 4; ++w4) {
            const float4 a = *(const float4*)&pool[w4][q][c0];
            const float4 c = *(const float4*)&pool[w4][q][c0 + 4];
            s[0] += a.x; s[1] += a.y; s[2] += a.z; s[3] += a.w;
            s[4] += c.x; s[5] += c.y; s[6] += c.z; s[7] += c.w;
        }
        union { unsigned int wd[4]; short8 v; } cb;
#pragma unroll
        for (int j = 0; j < 4; ++j)
            cb.wd[j] = cvtpk(s[2*j] * inv, s[2*j + 1] * inv);
        *(short8*)&Cb[q][c0] = cb.v;
    }
    __syncthreads();

    // W0 epilogue: wave w -> out cols 16w..16w+15 (W0f frag-order loads)
    f32x4 oacc[2] = {ZERO, ZERO};
#pragma unroll
    for (int s = 0; s < 2; ++s) {
        const short8 wf = *(const short8*)(W0f + (size_t)((w*2 + s)*64 + lane) * 8);
#pragma unroll
        for (int tt = 0; tt < 2; ++tt) {
            const short8 cf = *(const short8*)&Cb[tt*16 + n][s*32 + quad*8];
            oacc[tt] = MFMA16(cf, wf, oacc[tt]);
        }
    }
    const float bb = b0[16*w + n];
#pragma unroll
    for (int tt = 0; tt < 2; ++tt)
#pragma unroll
        for (int r = 0; r < 4; ++r)
            Out[((size_t)b * SEQ + q0 + tt*16 + quad*4 + r) * DI + 16*w + n] = oacc[tt][r] + bb;
}

// ---------------------------------------------------------------------------
extern "C" void kernel_launch(void* const* d_in, const int* in_sizes, int n_in,
                              void* d_out, int out_size, void* d_ws, size_t ws_size,
                              hipStream_t stream) {
    const float* X  = (const float*)d_in[0];
    const float* Wk = (const float*)d_in[1];
    const float* bk = (const float*)d_in[2];
    const float* Wq = (const float*)d_in[3];
    const float* bq = (const float*)d_in[4];
    const float* Wv = (const float*)d_in[5];
    const float* bv = (const float*)d_in[6];
    const float* W0 = (const float*)d_in[7];
    const float* b0 = (const float*)d_in[8];
    float* Out = (float*)d_out;

    unsigned char* ws = (unsigned char*)d_ws;
    unsigned short* Wf   = (unsigned short*)ws;                       // 384 KiB
    unsigned short* W0f  = (unsigned short*)(ws + 393216);            // 8 KiB
    float*          bcat = (float*)(ws + 401408);                     // 768 B
    unsigned short* Qf   = (unsigned short*)(ws + 409600);            // 2 MiB
    unsigned short* Kf   = (unsigned short*)(ws + 409600 + 2097152);  // 2 MiB
    unsigned short* Vf   = (unsigned short*)(ws + 409600 + 4194304);  // 2 MiB

    convert_kernel<<<98, 256, 0, stream>>>(Wq, Wk, Wv, W0, bq, bk, bv, Wf, W0f, bcat);
    proj_kernel<<<512, 256, 0, stream>>>(X, Wf, bcat, Qf, Kf, Vf);
    attn_kernel<<<512, 256, 0, stream>>>(Qf, Kf, Vf, W0f, b0, Out);
}